// Round 1
// baseline (407.440 us; speedup 1.0000x reference)
//
#include <hip/hip_runtime.h>

// out[idx0[idx1[idx2[i]]]] = x[i]  (indices are unique -> pure permutation scatter)
// Everything else in out is zero.

__global__ void zero_out_kernel(float4* __restrict__ out, long n4) {
    long i = (long)blockIdx.x * blockDim.x + threadIdx.x;
    if (i < n4) {
        out[i] = make_float4(0.f, 0.f, 0.f, 0.f);
    }
}

__global__ void scatter_rows_kernel(const float4* __restrict__ x,
                                    const int* __restrict__ idx0,
                                    const int* __restrict__ idx1,
                                    const int* __restrict__ idx2,
                                    float4* __restrict__ out,
                                    int n3) {
    int t = blockIdx.x * blockDim.x + threadIdx.x;
    int row = t >> 4;    // 16 float4 per 64-float row
    int c   = t & 15;
    if (row >= n3) return;
    // compose the three (collision-free) scatters: deepest first
    int j2 = idx2[row];   // position in [0, V2)
    int j1 = idx1[j2];    // position in [0, V1)
    int j0 = idx0[j1];    // position in [0, V0)
    out[(long)j0 * 16 + c] = x[(long)row * 16 + c];
}

extern "C" void kernel_launch(void* const* d_in, const int* in_sizes, int n_in,
                              void* d_out, int out_size, void* d_ws, size_t ws_size,
                              hipStream_t stream) {
    // setup_inputs order: x, idx0, idx1, idx2, v0, v1, v2
    const float* x    = (const float*)d_in[0];
    const int*   idx0 = (const int*)d_in[1];
    const int*   idx1 = (const int*)d_in[2];
    const int*   idx2 = (const int*)d_in[3];
    float* out = (float*)d_out;

    const int n3 = in_sizes[3];          // 25000 rows of x (idx2 has one entry per row)

    // 1) zero the whole output (write-BW bound: 409.6 MB)
    long n4 = (long)out_size / 4;        // number of float4 elements
    int  zblocks = (int)((n4 + 255) / 256);
    zero_out_kernel<<<zblocks, 256, 0, stream>>>((float4*)out, n4);

    // 2) scatter the 25000 rows (6.4 MB read + 6.4 MB write)
    int total = n3 * 16;                 // one thread per float4 of x
    int sblocks = (total + 255) / 256;
    scatter_rows_kernel<<<sblocks, 256, 0, stream>>>(
        (const float4*)x, idx0, idx1, idx2, (float4*)out, n3);
}